// Round 18
// baseline (98.573 us; speedup 1.0000x reference)
//
#include <hip/hip_runtime.h>

#define S_LEN 2048
#define DMODEL 1024
#define HEADS 8
#define DH 128
#define NQKV 6144
#define SCALE 0.08838834764831845f

typedef unsigned short u16;
typedef short s16x8 __attribute__((ext_vector_type(8)));
typedef short s16x4 __attribute__((ext_vector_type(4)));
typedef float f32x4 __attribute__((ext_vector_type(4)));

static __device__ __forceinline__ f32x4 mfma16(s16x8 a, s16x8 b, f32x4 c) {
  return __builtin_amdgcn_mfma_f32_16x16x32_bf16(a, b, c, 0, 0, 0);
}
static __device__ __forceinline__ u16 f2b(float f) {
  union { float f; unsigned u; } v; v.f = f;
  unsigned r = v.u + 0x7fffu + ((v.u >> 16) & 1u);
  return (u16)(r >> 16);
}
static __device__ __forceinline__ float b2f(u16 s) {
  union { unsigned u; float f; } v; v.u = ((unsigned)s) << 16;
  return v.f;
}
// async global->LDS, 16B per lane; lds dest = uniform base + lane*16
static __device__ __forceinline__ void gll16(const u16* g, u16* l) {
  __builtin_amdgcn_global_load_lds(
      (const __attribute__((address_space(1))) unsigned int*)g,
      (__attribute__((address_space(3))) unsigned int*)l, 16, 0, 0);
}

// Balanced partition, diag isolated: 60 slots/head (grid 480 <= 512 capacity,
// single generation). Every diag tile is its own 1-tile chunk.
static __device__ const int SQB[60] = {
  0,1, 2,2, 3,3, 4,4,4, 5,5,5, 6,6,6, 7,7,7,7, 8,8,8,8, 9,9,9,9,
  10,10,10,10,10, 11,11,11,11,11, 12,12,12,12,12,
  13,13,13,13,13,13, 14,14,14,14,14,14, 15,15,15,15,15,15};
static __device__ const int ST0[60] = {
  0, 0, 0,2, 0,3, 0,2,4, 0,3,5, 0,3,6, 0,3,5,7, 0,3,6,8, 0,3,6,9,
  0,3,6,8,10, 0,3,6,9,11, 0,3,6,9,12,
  0,3,6,9,11,13, 0,3,6,9,12,14, 0,3,6,9,12,15};
static __device__ const int SNT[60] = {
  1, 2, 2,1, 3,1, 2,2,1, 3,2,1, 3,3,1, 3,2,2,1, 3,3,2,1, 3,3,3,1,
  3,3,2,2,1, 3,3,3,2,1, 3,3,3,3,1,
  3,3,3,2,2,1, 3,3,3,3,2,1, 3,3,3,3,3,1};
// merge tables (qb>=2): storage prefix (slot-2 space) and chunk count
static __device__ const int S0T2[16] = {0,0,0,2,4,7,10,13,17,21,25,30,35,40,46,52};
static __device__ const int NCT2[16] = {0,0,2,2,3,3,3,4,4,4,5,5,5,6,6,6};

// ------------------------------------------- fused preprocessing (1 launch):
// blocks [0,2048): cast x -> bf16 (float4 loads)
// blocks [2048,3584): transpose+cast wqkv (64x64 tiles, float4 in / s16x8 out)
// blocks [3584,3840): transpose+cast wout
__global__ void __launch_bounds__(256)
k_prep(const float* __restrict__ x, const float* __restrict__ wqkv,
       const float* __restrict__ wout, u16* __restrict__ xb,
       u16* __restrict__ wqT, u16* __restrict__ woT) {
  const int bid = blockIdx.x, tid = threadIdx.x;
  if (bid < 2048) {
    int i = bid * 256 + tid;
    float4 v = reinterpret_cast<const float4*>(x)[i];
    s16x4 o;
    o[0] = (short)f2b(v.x); o[1] = (short)f2b(v.y);
    o[2] = (short)f2b(v.z); o[3] = (short)f2b(v.w);
    reinterpret_cast<s16x4*>(xb)[i] = o;
    return;
  }
  __shared__ float tile[64][65];
  const float* in;
  u16* out;
  int C, c0, r0;
  if (bid < 3584) {
    int j = bid - 2048;                 // 96 x 16 tiles
    in = wqkv; out = wqT; C = NQKV;
    c0 = (j % 96) * 64; r0 = (j / 96) * 64;
  } else {
    int j = bid - 3584;                 // 16 x 16 tiles
    in = wout; out = woT; C = DMODEL;
    c0 = (j & 15) * 64; r0 = (j >> 4) * 64;
  }
  const int rr = tid >> 4, cq = (tid & 15) * 4;
#pragma unroll
  for (int p = 0; p < 4; p++) {
    int r = rr + p * 16;
    float4 v = *reinterpret_cast<const float4*>(in + (size_t)(r0 + r) * C + c0 + cq);
    tile[r][cq] = v.x; tile[r][cq + 1] = v.y;
    tile[r][cq + 2] = v.z; tile[r][cq + 3] = v.w;
  }
  __syncthreads();
  const int cc = tid >> 3, rq = (tid & 7) * 8;
#pragma unroll
  for (int p = 0; p < 2; p++) {
    int c = cc + p * 32;
    s16x8 o;
#pragma unroll
    for (int jj = 0; jj < 8; jj++) o[jj] = (short)f2b(tile[rq + jj][c]);
    *reinterpret_cast<s16x8*>(out + (size_t)(c0 + c) * DMODEL + r0 + rq) = o;
  }
}

// ---------------------------------------------------------------- GEMM (m97-style)
// MODE 0: C[2048,6144] = xb @ wqT^T, 128x128 tiles, 1-D grid 768, head==XCD
//         swizzle; t in {2,5} stored transposed; scale t in {0,3}.
// MODE 1: C[2048,1024] = obuf @ woT^T -> f32, 64x128 tiles, grid (8,32) = 256.
// r18: launch_bounds(256,4) (4 blocks/CU; LDS 32KB allows it) + per-half
// fragment loads (halves operand liveness so 128-VGPR budget fits spill-free).
template <int MODE>
__global__ void __launch_bounds__(256, 4)
k_gemm2(const u16* __restrict__ A, const u16* __restrict__ Bt,
        u16* __restrict__ outb, float* __restrict__ outf) {
  const int tid = threadIdx.x;
  const int w = tid >> 6, l = tid & 63;
  const int lr = l & 15, lg = l >> 4;
  if (MODE == 0) {
    __shared__ u16 As[128 * 64];
    __shared__ u16 Bs[128 * 64];
    int m = blockIdx.x / 48, j = blockIdx.x % 48;
    int n = (j & 7) + 8 * (j >> 3);  // XCD (j&7) owns all n with n&7==j&7
    int m0 = m * 128, n0 = n * 128;
    const int wm = (w >> 1) * 64, wn = (w & 1) * 64;
    f32x4 acc[4][4] = {};
    for (int k0 = 0; k0 < DMODEL; k0 += 64) {
      __syncthreads();
#pragma unroll
      for (int jj = 0; jj < 8; jj++) {
        int c = w * 8 + jj;
        int cc = c & 15;
        int r = cc * 8 + (l >> 3);
        int s = l & 7;
        const u16* src = (c < 16 ? A + (size_t)(m0 + r) * DMODEL
                                 : Bt + (size_t)(n0 + r) * DMODEL)
                         + k0 + ((s ^ (r & 7)) * 8);
        gll16(src, (c < 16 ? As : Bs) + cc * 8 * 64);
      }
      asm volatile("s_waitcnt vmcnt(0)" ::: "memory");
      __syncthreads();
#pragma unroll
      for (int hh = 0; hh < 2; hh++) {
        s16x8 a[4], b[4];
#pragma unroll
        for (int i = 0; i < 4; i++) {
          int ra = wm + i * 16 + lr;
          int oa = (ra * 128 + hh * 64 + lg * 16) ^ ((lr & 7) << 4);
          a[i] = *reinterpret_cast<const s16x8*>((const char*)As + oa);
          int rb = wn + i * 16 + lr;
          int ob = (rb * 128 + hh * 64 + lg * 16) ^ ((lr & 7) << 4);
          b[i] = *reinterpret_cast<const s16x8*>((const char*)Bs + ob);
        }
#pragma unroll
        for (int i = 0; i < 4; i++)
#pragma unroll
          for (int jj = 0; jj < 4; jj++)
            acc[i][jj] = mfma16(a[i], b[jj], acc[i][jj]);
      }
    }
    const int t = n >> 3, h = n & 7;
    u16* dst = outb + (size_t)(t * HEADS + h) * S_LEN * DH;
    if (t == 2 || t == 5) {
#pragma unroll
      for (int i = 0; i < 4; i++)
#pragma unroll
        for (int jj = 0; jj < 4; jj++) {
          int col = wn + jj * 16 + lr;
          int row0 = m0 + wm + i * 16 + lg * 4;
          s16x4 p;
#pragma unroll
          for (int e = 0; e < 4; e++) p[e] = (short)f2b(acc[i][jj][e]);
          *reinterpret_cast<s16x4*>(dst + (size_t)col * S_LEN + row0) = p;
        }
    } else {
      const float sc = (t == 0 || t == 3) ? SCALE : 1.0f;
#pragma unroll
      for (int i = 0; i < 4; i++)
#pragma unroll
        for (int jj = 0; jj < 4; jj++)
#pragma unroll
          for (int e = 0; e < 4; e++) {
            int row = m0 + wm + i * 16 + lg * 4 + e;
            int col = wn + jj * 16 + lr;
            dst[(size_t)row * DH + col] = f2b(acc[i][jj][e] * sc);
          }
    }
  } else {
    // 64x128 tile: A chunks 0..7 (64 rows), B chunks 8..23 (128 rows)
    __shared__ u16 As[64 * 64];
    __shared__ u16 Bs[128 * 64];
    int m0 = blockIdx.y * 64, n0 = blockIdx.x * 128;
    const int wm = (w >> 1) * 32, wn = (w & 1) * 64;
    f32x4 acc[2][4] = {};
    for (int k0 = 0; k0 < DMODEL; k0 += 64) {
      __syncthreads();
#pragma unroll
      for (int jj = 0; jj < 8; jj++) {
        int c = w * 8 + jj;
        if (c < 24) {
          int isA = (c < 8);
          int cc = isA ? c : c - 8;
          int r = cc * 8 + (l >> 3);
          int s = l & 7;
          const u16* src = (isA ? A + (size_t)(m0 + r) * DMODEL
                                : Bt + (size_t)(n0 + r) * DMODEL)
                           + k0 + ((s ^ (r & 7)) * 8);
          gll16(src, (isA ? As : Bs) + cc * 8 * 64);
        }
      }
      asm volatile("s_waitcnt vmcnt(0)" ::: "memory");
      __syncthreads();
#pragma unroll
      for (int hh = 0; hh < 2; hh++) {
        s16x8 a[2], b[4];
#pragma unroll
        for (int i = 0; i < 2; i++) {
          int ra = wm + i * 16 + lr;
          int oa = (ra * 128 + hh * 64 + lg * 16) ^ ((lr & 7) << 4);
          a[i] = *reinterpret_cast<const s16x8*>((const char*)As + oa);
        }
#pragma unroll
        for (int i = 0; i < 4; i++) {
          int rb = wn + i * 16 + lr;
          int ob = (rb * 128 + hh * 64 + lg * 16) ^ ((lr & 7) << 4);
          b[i] = *reinterpret_cast<const s16x8*>((const char*)Bs + ob);
        }
#pragma unroll
        for (int i = 0; i < 2; i++)
#pragma unroll
          for (int jj = 0; jj < 4; jj++)
            acc[i][jj] = mfma16(a[i], b[jj], acc[i][jj]);
      }
    }
#pragma unroll
    for (int i = 0; i < 2; i++)
#pragma unroll
      for (int jj = 0; jj < 4; jj++)
#pragma unroll
        for (int e = 0; e < 4; e++) {
          int row = m0 + wm + i * 16 + lg * 4 + e;
          int col = n0 + wn + jj * 16 + lr;
          outf[(size_t)row * DMODEL + col] = acc[i][jj][e];
        }
  }
}

// ---------------------------------------------------------------- attention phase 1
// Fused diag + balanced slots: grid 480 = 60 slots/head, h = bid&7.
__global__ void __launch_bounds__(512, 2)
k_attn1(const u16* __restrict__ qkvb, u16* __restrict__ op,
        float* __restrict__ ml, u16* __restrict__ obuf) {
  __shared__ u16 KA[128 * 128];   // K tile   [key j][d]   (swizzled content)
  __shared__ u16 VB[128 * 128];   // V^T tile [d][key j]   (swizzled content)
  __shared__ u16 PB[128][42];     // P quarter, wave-private rows
  const int h = blockIdx.x & 7, slot = blockIdx.x >> 3;
  const int qb = SQB[slot];
  const int t0 = ST0[slot];
  const int ntile = SNT[slot];
  const bool hasDiag = (t0 + ntile - 1 == qb);
  const int tid = threadIdx.x;
  const int w = tid >> 6, l = tid & 63;
  const int lr = l & 15, lg = l >> 4;
  const size_t hs = (size_t)S_LEN * DH;
  const u16* qu  = qkvb + (size_t)(0 * HEADS + h) * hs;
  const u16* ku  = qkvb + (size_t)(1 * HEADS + h) * hs;
  const u16* vuT = qkvb + (size_t)(2 * HEADS + h) * hs;  // [128][2048]
  const u16* qc  = qkvb + (size_t)(3 * HEADS + h) * hs;
  const u16* kc  = qkvb + (size_t)(4 * HEADS + h) * hs;
  const u16* vcT = qkvb + (size_t)(5 * HEADS + h) * hs;  // [128][2048]
  const int rq = qb * 128 + w * 16;

  f32x4 accO[8] = {};
  f32x4 accS[8];
  f32x4 corrF[8] = {};
  float mrun[4], lrun[4];
#pragma unroll
  for (int e = 0; e < 4; e++) { mrun[e] = -INFINITY; lrun[e] = 0.f; }

  auto stageK = [&](const u16* kbase, int t) {
#pragma unroll
    for (int i = 0; i < 4; i++) {
      int r = w * 16 + i * 4 + (l >> 4);
      int s = l & 15;
      gll16(kbase + (size_t)t * 128 * DH + r * DH + ((s ^ (r & 15)) * 8),
            KA + (w * 16 + i * 4) * 128);
    }
  };
  auto stageV = [&](const u16* vbase, int t) {
#pragma unroll
    for (int i = 0; i < 4; i++) {
      int r = w * 16 + i * 4 + (l >> 4);
      int s = l & 15;
      gll16(vbase + (size_t)r * S_LEN + t * 128 + ((s ^ (r & 15)) * 8),
            VB + (w * 16 + i * 4) * 128);
    }
  };

  // ---- fused diag-correction prologue (block-uniform branch)
  if (hasDiag) {
    stageK(ku, qb);
    stageV(vuT, qb);
    s16x8 aqu[4];
#pragma unroll
    for (int ks = 0; ks < 4; ks++)
      aqu[ks] = *reinterpret_cast<const s16x8*>(
          qu + (size_t)(rq + lr) * DH + ks * 32 + lg * 8);
    asm volatile("s_waitcnt vmcnt(4)" ::: "memory");  // K_u in
    __syncthreads();
    f32x4 s2[8] = {};
#pragma unroll
    for (int ks = 0; ks < 4; ks++)
#pragma unroll
      for (int nf = 0; nf < 8; nf++) {
        int o = ((nf * 16 + lr) * 256 + ks * 64 + lg * 16) ^ (lr << 4);
        s16x8 b = *reinterpret_cast<const s16x8*>((const char*)KA + o);
        s2[nf] = mfma16(aqu[ks], b, s2[nf]);
      }
    asm volatile("s_waitcnt vmcnt(0)" ::: "memory");  // V_u in
    __syncthreads();
#pragma unroll
    for (int qq = 0; qq < 4; qq++) {
#pragma unroll
      for (int jj = 0; jj < 2; jj++)
#pragma unroll
        for (int e = 0; e < 4; e++) {
          int rowq = w * 16 + lg * 4 + e;
          int col = (qq * 2 + jj) * 16 + lr;
          float x = s2[qq * 2 + jj][e];
          PB[w * 16 + lg * 4 + e][jj * 16 + lr] =
              f2b((col > rowq) ? 1.f / (1.f + __expf(-x)) : 0.f);
        }
      s16x8 p = *reinterpret_cast<const s16x8*>(&PB[w * 16 + lr][lg * 8]);
#pragma unroll
      for (int nf = 0; nf < 8; nf++) {
        int o = ((nf * 16 + lr) * 256 + qq * 64 + lg * 16) ^ (lr << 4);
        s16x8 bv = *reinterpret_cast<const s16x8*>((const char*)VB + o);
        corrF[nf] = mfma16(p, bv, corrF[nf]);
      }
    }
#pragma unroll
    for (int nf = 0; nf < 8; nf++)
#pragma unroll
      for (int e = 0; e < 4; e++) {
        float x = corrF[nf][e];
        corrF[nf][e] = x / (1.f + __expf(-x));  // silu, kept in f32
      }
    __syncthreads();  // all waves done with KA/VB before main restage
  }

  // Q fragments in registers (once per slot)
  s16x8 aq[4];
#pragma unroll
  for (int ks = 0; ks < 4; ks++)
    aq[ks] = *reinterpret_cast<const s16x8*>(
        qc + (size_t)(rq + lr) * DH + ks * 32 + lg * 8);

  auto qkTile = [&](bool dg) {
#pragma unroll
    for (int nf = 0; nf < 8; nf++) accS[nf] = f32x4{0.f, 0.f, 0.f, 0.f};
#pragma unroll
    for (int ks = 0; ks < 4; ks++)
#pragma unroll
      for (int nf = 0; nf < 8; nf++) {
        int o = ((nf * 16 + lr) * 256 + ks * 64 + lg * 16) ^ (lr << 4);
        s16x8 b = *reinterpret_cast<const s16x8*>((const char*)KA + o);
        accS[nf] = mfma16(aq[ks], b, accS[nf]);
      }
    if (dg) {
#pragma unroll
      for (int nf = 0; nf < 8; nf++)
#pragma unroll
        for (int e = 0; e < 4; e++) {
          int rowq = w * 16 + lg * 4 + e;
          int col = nf * 16 + lr;
          if (col > rowq) accS[nf][e] = -INFINITY;
          else accS[nf][e] -= corrF[nf][e];
        }
    }
    // online softmax
#pragma unroll
    for (int e = 0; e < 4; e++) {
      float mx = accS[0][e];
#pragma unroll
      for (int nf = 1; nf < 8; nf++) mx = fmaxf(mx, accS[nf][e]);
#pragma unroll
      for (int off = 1; off < 16; off <<= 1) mx = fmaxf(mx, __shfl_xor(mx, off, 64));
      float mnew = fmaxf(mrun[e], mx);
      float f = __expf(mrun[e] - mnew);
      float rs = 0.f;
#pragma unroll
      for (int nf = 0; nf < 8; nf++) {
        float p = __expf(accS[nf][e] - mnew);
        accS[nf][e] = p;
        rs += p;
      }
#pragma unroll
      for (int off = 1; off < 16; off <<= 1) rs += __shfl_xor(rs, off, 64);
      lrun[e] = lrun[e] * f + rs;
      mrun[e] = mnew;
#pragma unroll
      for (int nf = 0; nf < 8; nf++) accO[nf][e] *= f;
    }
  };
  auto pvTile = [&]() {
#pragma unroll
    for (int qq = 0; qq < 4; qq++) {   // 32-key quarters; PB wave-private
#pragma unroll
      for (int jj = 0; jj < 2; jj++)
#pragma unroll
        for (int e = 0; e < 4; e++)
          PB[w * 16 + lg * 4 + e][jj * 16 + lr] = f2b(accS[qq * 2 + jj][e]);
      s16x8 p = *reinterpret_cast<const s16x8*>(&PB[w * 16 + lr][lg * 8]);
#pragma unroll
      for (int nf = 0; nf < 8; nf++) {
        int o = ((nf * 16 + lr) * 256 + qq * 64 + lg * 16) ^ (lr << 4);
        s16x8 bv = *reinterpret_cast<const s16x8*>((const char*)VB + o);
        accO[nf] = mfma16(p, bv, accO[nf]);
      }
    }
  };

  stageK(kc, t0);
  stageV(vcT, t0);
  asm volatile("s_waitcnt vmcnt(4)" ::: "memory");  // K(t0) in; V in flight
  __syncthreads();
  for (int i = 0; i < ntile; i++) {
    qkTile(t0 + i == qb);                            // V(i) lands under this
    asm volatile("s_waitcnt vmcnt(0)" ::: "memory"); // V(i) in
    __syncthreads();                                 // all waves done with KA
    if (i + 1 < ntile) stageK(kc, t0 + i + 1);       // overwrite KA
    pvTile();                                        // K(i+1) lands under this
    asm volatile("s_waitcnt vmcnt(0)" ::: "memory"); // K(i+1) in
    __syncthreads();                                 // all waves done with VB
    if (i + 1 < ntile) stageV(vcT, t0 + i + 1);      // overwrite VB
  }

  if (slot < 2) {
    // single-chunk slot (qb 0,1): normalize and write obuf directly
#pragma unroll
    for (int nf = 0; nf < 8; nf++)
#pragma unroll
      for (int e = 0; e < 4; e++) {
        int row = w * 16 + lg * 4 + e;
        KA[row * 128 + nf * 16 + lr] = f2b(accO[nf][e] / lrun[e]);
      }
    __syncthreads();
#pragma unroll
    for (int i = 0; i < 4; i++) {
      int idx = tid + i * 512;          // 2048 x s16x8 covers 128x128
      int row = idx >> 4, c8 = (idx & 15) * 8;
      *reinterpret_cast<s16x8*>(obuf + (size_t)(qb * 128 + row) * DMODEL +
                                h * DH + c8) =
          reinterpret_cast<const s16x8*>(KA)[idx];
    }
  } else {
    // coalesced partial writeout: accO -> KA (LDS) -> global
#pragma unroll
    for (int nf = 0; nf < 8; nf++)
#pragma unroll
      for (int e = 0; e < 4; e++) {
        int row = w * 16 + lg * 4 + e;
        KA[row * 128 + nf * 16 + lr] = f2b(accO[nf][e]);
      }
    __syncthreads();
    const int gs = h * 58 + slot - 2;   // 464 storage slots
    u16* dst = op + (size_t)gs * 16384;
#pragma unroll
    for (int i = 0; i < 4; i++)
      reinterpret_cast<s16x8*>(dst)[tid + i * 512] =
          reinterpret_cast<const s16x8*>(KA)[tid + i * 512];
    if (lr == 0) {
      float* mlp = ml + (size_t)gs * 256;
#pragma unroll
      for (int e = 0; e < 4; e++) {
        int row = w * 16 + lg * 4 + e;
        mlp[row] = mrun[e];
        mlp[128 + row] = lrun[e];
      }
    }
  }
}

// ---------------------------------------------------------------- phase 2 merge
// grid 112: h = bid&7, qb = 2 + (bid>>3). Chunk c of qb is storage slot
// gs = h*58 + S0T2[qb] + c.
__global__ void __launch_bounds__(256)
k_attn2(const u16* __restrict__ op, const float* __restrict__ ml,
        u16* __restrict__ obuf) {
  const int h = blockIdx.x & 7, qb = 2 + (blockIdx.x >> 3);
  const int nc = NCT2[qb];
  const int base = h * 58 + S0T2[qb];
  const int row = threadIdx.x >> 1, c0 = (threadIdx.x & 1) * 64;
  float mg = -INFINITY;
  for (int c = 0; c < nc; c++) mg = fmaxf(mg, ml[(size_t)(base + c) * 256 + row]);
  float acc[64];
#pragma unroll
  for (int k = 0; k < 64; k++) acc[k] = 0.f;
  float lsum = 0.f;
  for (int c = 0; c < nc; c++) {
    int gs = base + c;
    const float* mlp = ml + (size_t)gs * 256;
    float f = __expf(mlp[row] - mg);
    lsum += f * mlp[128 + row];
    const u16* p = op + (size_t)gs * 16384 + row * 128 + c0;
#pragma unroll
    for (int k = 0; k < 8; k++) {
      s16x8 v = *reinterpret_cast<const s16x8*>(p + k * 8);
#pragma unroll
      for (int j = 0; j < 8; j++) acc[k * 8 + j] += f * b2f((u16)v[j]);
    }
  }
  float inv = 1.f / lsum;
  u16* dst = obuf + (size_t)(qb * 128 + row) * DMODEL + h * DH + c0;
#pragma unroll
  for (int k = 0; k < 8; k++) {
    s16x8 o;
#pragma unroll
    for (int j = 0; j < 8; j++) o[j] = (short)f2b(acc[k * 8 + j] * inv);
    *reinterpret_cast<s16x8*>(dst + k * 8) = o;
  }
}

// ---------------------------------------------------------------- launcher
extern "C" void kernel_launch(void* const* d_in, const int* in_sizes, int n_in,
                              void* d_out, int out_size, void* d_ws, size_t ws_size,
                              hipStream_t stream) {
  (void)in_sizes; (void)n_in; (void)out_size; (void)ws_size;
  const float* x = (const float*)d_in[0];
  const float* wqkv = (const float*)d_in[1];
  const float* wout = (const float*)d_in[2];
  char* ws = (char*)d_ws;
  u16* xb    = (u16*)(ws + 0);          // 4 MB; dead after gemm0
  u16* wqT   = (u16*)(ws + 4194304);    // 12.58 MB; dead after gemm0
  u16* opb   = (u16*)(ws + 0);          // partials: 464 slots * 32 KB = 15.2 MB
  float* mlb = (float*)(ws + 15990784); // 464 * 256 * 4 = 0.48 MB
  u16* woT   = (u16*)(ws + 16777216);   // 2 MB (live until gemm1)
  u16* qkvb  = (u16*)(ws + 18874368);   // 24 MB: [qu|ku|vuT|qc|kc|vcT]
  u16* obuf  = (u16*)(ws + 44040192);   // 4 MB
  float* out = (float*)d_out;

  k_prep<<<3840, 256, 0, stream>>>(x, wqkv, wout, xb, wqT, woT);
  k_gemm2<0><<<768, 256, 0, stream>>>(xb, wqT, qkvb, nullptr);
  k_attn1<<<480, 512, 0, stream>>>(qkvb, opb, mlb, obuf);
  k_attn2<<<112, 256, 0, stream>>>(opb, mlb, obuf);
  k_gemm2<1><<<dim3(8, 32), 256, 0, stream>>>(obuf, woT, nullptr, out);
}

// Round 19
// 97.635 us; speedup vs baseline: 1.0096x; 1.0096x over previous
//
#include <hip/hip_runtime.h>

#define S_LEN 2048
#define DMODEL 1024
#define HEADS 8
#define DH 128
#define NQKV 6144
#define SCALE 0.08838834764831845f

typedef unsigned short u16;
typedef short s16x8 __attribute__((ext_vector_type(8)));
typedef short s16x4 __attribute__((ext_vector_type(4)));
typedef float f32x4 __attribute__((ext_vector_type(4)));

static __device__ __forceinline__ f32x4 mfma16(s16x8 a, s16x8 b, f32x4 c) {
  return __builtin_amdgcn_mfma_f32_16x16x32_bf16(a, b, c, 0, 0, 0);
}
static __device__ __forceinline__ u16 f2b(float f) {
  union { float f; unsigned u; } v; v.f = f;
  unsigned r = v.u + 0x7fffu + ((v.u >> 16) & 1u);
  return (u16)(r >> 16);
}
static __device__ __forceinline__ float b2f(u16 s) {
  union { unsigned u; float f; } v; v.u = ((unsigned)s) << 16;
  return v.f;
}
// async global->LDS, 16B per lane; lds dest = uniform base + lane*16
static __device__ __forceinline__ void gll16(const u16* g, u16* l) {
  __builtin_amdgcn_global_load_lds(
      (const __attribute__((address_space(1))) unsigned int*)g,
      (__attribute__((address_space(3))) unsigned int*)l, 16, 0, 0);
}

// Balanced partition, diag isolated: 60 slots/head (grid 480 <= 512 capacity,
// single generation). Every diag tile is its own 1-tile chunk.
static __device__ const int SQB[60] = {
  0,1, 2,2, 3,3, 4,4,4, 5,5,5, 6,6,6, 7,7,7,7, 8,8,8,8, 9,9,9,9,
  10,10,10,10,10, 11,11,11,11,11, 12,12,12,12,12,
  13,13,13,13,13,13, 14,14,14,14,14,14, 15,15,15,15,15,15};
static __device__ const int ST0[60] = {
  0, 0, 0,2, 0,3, 0,2,4, 0,3,5, 0,3,6, 0,3,5,7, 0,3,6,8, 0,3,6,9,
  0,3,6,8,10, 0,3,6,9,11, 0,3,6,9,12,
  0,3,6,9,11,13, 0,3,6,9,12,14, 0,3,6,9,12,15};
static __device__ const int SNT[60] = {
  1, 2, 2,1, 3,1, 2,2,1, 3,2,1, 3,3,1, 3,2,2,1, 3,3,2,1, 3,3,3,1,
  3,3,2,2,1, 3,3,3,2,1, 3,3,3,3,1,
  3,3,3,2,2,1, 3,3,3,3,2,1, 3,3,3,3,3,1};
// merge tables (qb>=2): storage prefix (slot-2 space) and chunk count
static __device__ const int S0T2[16] = {0,0,0,2,4,7,10,13,17,21,25,30,35,40,46,52};
static __device__ const int NCT2[16] = {0,0,2,2,3,3,3,4,4,4,5,5,5,6,6,6};

// ------------------------------------------- fused preprocessing (1 launch):
// blocks [0,2048): cast x -> bf16 (float4 loads)
// blocks [2048,3584): transpose+cast wqkv (64x64 tiles, float4 in / s16x8 out)
// blocks [3584,3840): transpose+cast wout
__global__ void __launch_bounds__(256)
k_prep(const float* __restrict__ x, const float* __restrict__ wqkv,
       const float* __restrict__ wout, u16* __restrict__ xb,
       u16* __restrict__ wqT, u16* __restrict__ woT) {
  const int bid = blockIdx.x, tid = threadIdx.x;
  if (bid < 2048) {
    int i = bid * 256 + tid;
    float4 v = reinterpret_cast<const float4*>(x)[i];
    s16x4 o;
    o[0] = (short)f2b(v.x); o[1] = (short)f2b(v.y);
    o[2] = (short)f2b(v.z); o[3] = (short)f2b(v.w);
    reinterpret_cast<s16x4*>(xb)[i] = o;
    return;
  }
  __shared__ float tile[64][65];
  const float* in;
  u16* out;
  int C, c0, r0;
  if (bid < 3584) {
    int j = bid - 2048;                 // 96 x 16 tiles
    in = wqkv; out = wqT; C = NQKV;
    c0 = (j % 96) * 64; r0 = (j / 96) * 64;
  } else {
    int j = bid - 3584;                 // 16 x 16 tiles
    in = wout; out = woT; C = DMODEL;
    c0 = (j & 15) * 64; r0 = (j >> 4) * 64;
  }
  const int rr = tid >> 4, cq = (tid & 15) * 4;
#pragma unroll
  for (int p = 0; p < 4; p++) {
    int r = rr + p * 16;
    float4 v = *reinterpret_cast<const float4*>(in + (size_t)(r0 + r) * C + c0 + cq);
    tile[r][cq] = v.x; tile[r][cq + 1] = v.y;
    tile[r][cq + 2] = v.z; tile[r][cq + 3] = v.w;
  }
  __syncthreads();
  const int cc = tid >> 3, rq = (tid & 7) * 8;
#pragma unroll
  for (int p = 0; p < 2; p++) {
    int c = cc + p * 32;
    s16x8 o;
#pragma unroll
    for (int jj = 0; jj < 8; jj++) o[jj] = (short)f2b(tile[rq + jj][c]);
    *reinterpret_cast<s16x8*>(out + (size_t)(c0 + c) * DMODEL + r0 + rq) = o;
  }
}

// ---------------------------------------------------------------- GEMM (m97-style)
// MODE 0: C[2048,6144] = xb @ wqT^T, 128x128 tiles, 1-D grid 768, head==XCD
//         swizzle; t in {2,5} stored transposed; scale t in {0,3}.
// MODE 1: C[2048,1024] = obuf @ woT^T -> f32, 64x128 tiles, grid (8,32) = 256.
template <int MODE>
__global__ void __launch_bounds__(256, 3)
k_gemm2(const u16* __restrict__ A, const u16* __restrict__ Bt,
        u16* __restrict__ outb, float* __restrict__ outf) {
  const int tid = threadIdx.x;
  const int w = tid >> 6, l = tid & 63;
  const int lr = l & 15, lg = l >> 4;
  if (MODE == 0) {
    __shared__ u16 As[128 * 64];
    __shared__ u16 Bs[128 * 64];
    int m = blockIdx.x / 48, j = blockIdx.x % 48;
    int n = (j & 7) + 8 * (j >> 3);  // XCD (j&7) owns all n with n&7==j&7
    int m0 = m * 128, n0 = n * 128;
    const int wm = (w >> 1) * 64, wn = (w & 1) * 64;
    f32x4 acc[4][4] = {};
    for (int k0 = 0; k0 < DMODEL; k0 += 64) {
      __syncthreads();
#pragma unroll
      for (int jj = 0; jj < 8; jj++) {
        int c = w * 8 + jj;
        int cc = c & 15;
        int r = cc * 8 + (l >> 3);
        int s = l & 7;
        const u16* src = (c < 16 ? A + (size_t)(m0 + r) * DMODEL
                                 : Bt + (size_t)(n0 + r) * DMODEL)
                         + k0 + ((s ^ (r & 7)) * 8);
        gll16(src, (c < 16 ? As : Bs) + cc * 8 * 64);
      }
      asm volatile("s_waitcnt vmcnt(0)" ::: "memory");
      __syncthreads();
      s16x8 a[2][4], b[2][4];
#pragma unroll
      for (int hh = 0; hh < 2; hh++)
#pragma unroll
        for (int i = 0; i < 4; i++) {
          int ra = wm + i * 16 + lr;
          int oa = (ra * 128 + hh * 64 + lg * 16) ^ ((lr & 7) << 4);
          a[hh][i] = *reinterpret_cast<const s16x8*>((const char*)As + oa);
          int rb = wn + i * 16 + lr;
          int ob = (rb * 128 + hh * 64 + lg * 16) ^ ((lr & 7) << 4);
          b[hh][i] = *reinterpret_cast<const s16x8*>((const char*)Bs + ob);
        }
#pragma unroll
      for (int hh = 0; hh < 2; hh++)
#pragma unroll
        for (int i = 0; i < 4; i++)
#pragma unroll
          for (int jj = 0; jj < 4; jj++)
            acc[i][jj] = mfma16(a[hh][i], b[hh][jj], acc[i][jj]);
    }
    const int t = n >> 3, h = n & 7;
    u16* dst = outb + (size_t)(t * HEADS + h) * S_LEN * DH;
    if (t == 2 || t == 5) {
#pragma unroll
      for (int i = 0; i < 4; i++)
#pragma unroll
        for (int jj = 0; jj < 4; jj++) {
          int col = wn + jj * 16 + lr;
          int row0 = m0 + wm + i * 16 + lg * 4;
          s16x4 p;
#pragma unroll
          for (int e = 0; e < 4; e++) p[e] = (short)f2b(acc[i][jj][e]);
          *reinterpret_cast<s16x4*>(dst + (size_t)col * S_LEN + row0) = p;
        }
    } else {
      const float sc = (t == 0 || t == 3) ? SCALE : 1.0f;
#pragma unroll
      for (int i = 0; i < 4; i++)
#pragma unroll
        for (int jj = 0; jj < 4; jj++)
#pragma unroll
          for (int e = 0; e < 4; e++) {
            int row = m0 + wm + i * 16 + lg * 4 + e;
            int col = wn + jj * 16 + lr;
            dst[(size_t)row * DH + col] = f2b(acc[i][jj][e] * sc);
          }
    }
  } else {
    // 64x128 tile: A chunks 0..7 (64 rows), B chunks 8..23 (128 rows)
    __shared__ u16 As[64 * 64];
    __shared__ u16 Bs[128 * 64];
    int m0 = blockIdx.y * 64, n0 = blockIdx.x * 128;
    const int wm = (w >> 1) * 32, wn = (w & 1) * 64;
    f32x4 acc[2][4] = {};
    for (int k0 = 0; k0 < DMODEL; k0 += 64) {
      __syncthreads();
#pragma unroll
      for (int jj = 0; jj < 8; jj++) {
        int c = w * 8 + jj;
        if (c < 24) {
          int isA = (c < 8);
          int cc = isA ? c : c - 8;
          int r = cc * 8 + (l >> 3);
          int s = l & 7;
          const u16* src = (isA ? A + (size_t)(m0 + r) * DMODEL
                                : Bt + (size_t)(n0 + r) * DMODEL)
                           + k0 + ((s ^ (r & 7)) * 8);
          gll16(src, (isA ? As : Bs) + cc * 8 * 64);
        }
      }
      asm volatile("s_waitcnt vmcnt(0)" ::: "memory");
      __syncthreads();
      s16x8 a[2][2], b[2][4];
#pragma unroll
      for (int hh = 0; hh < 2; hh++) {
#pragma unroll
        for (int i = 0; i < 2; i++) {
          int ra = wm + i * 16 + lr;
          int oa = (ra * 128 + hh * 64 + lg * 16) ^ ((lr & 7) << 4);
          a[hh][i] = *reinterpret_cast<const s16x8*>((const char*)As + oa);
        }
#pragma unroll
        for (int i = 0; i < 4; i++) {
          int rb = wn + i * 16 + lr;
          int ob = (rb * 128 + hh * 64 + lg * 16) ^ ((lr & 7) << 4);
          b[hh][i] = *reinterpret_cast<const s16x8*>((const char*)Bs + ob);
        }
      }
#pragma unroll
      for (int hh = 0; hh < 2; hh++)
#pragma unroll
        for (int i = 0; i < 2; i++)
#pragma unroll
          for (int jj = 0; jj < 4; jj++)
            acc[i][jj] = mfma16(a[hh][i], b[hh][jj], acc[i][jj]);
    }
#pragma unroll
    for (int i = 0; i < 2; i++)
#pragma unroll
      for (int jj = 0; jj < 4; jj++)
#pragma unroll
        for (int e = 0; e < 4; e++) {
          int row = m0 + wm + i * 16 + lg * 4 + e;
          int col = n0 + wn + jj * 16 + lr;
          outf[(size_t)row * DMODEL + col] = acc[i][jj][e];
        }
  }
}

// ---------------------------------------------------------------- attention phase 1
// Fused diag + balanced slots: grid 480 = 60 slots/head, h = bid&7.
__global__ void __launch_bounds__(512, 2)
k_attn1(const u16* __restrict__ qkvb, u16* __restrict__ op,
        float* __restrict__ ml, u16* __restrict__ obuf) {
  __shared__ u16 KA[128 * 128];   // K tile   [key j][d]   (swizzled content)
  __shared__ u16 VB[128 * 128];   // V^T tile [d][key j]   (swizzled content)
  __shared__ u16 PB[128][42];     // P quarter, wave-private rows
  const int h = blockIdx.x & 7, slot = blockIdx.x >> 3;
  const int qb = SQB[slot];
  const int t0 = ST0[slot];
  const int ntile = SNT[slot];
  const bool hasDiag = (t0 + ntile - 1 == qb);
  const int tid = threadIdx.x;
  const int w = tid >> 6, l = tid & 63;
  const int lr = l & 15, lg = l >> 4;
  const size_t hs = (size_t)S_LEN * DH;
  const u16* qu  = qkvb + (size_t)(0 * HEADS + h) * hs;
  const u16* ku  = qkvb + (size_t)(1 * HEADS + h) * hs;
  const u16* vuT = qkvb + (size_t)(2 * HEADS + h) * hs;  // [128][2048]
  const u16* qc  = qkvb + (size_t)(3 * HEADS + h) * hs;
  const u16* kc  = qkvb + (size_t)(4 * HEADS + h) * hs;
  const u16* vcT = qkvb + (size_t)(5 * HEADS + h) * hs;  // [128][2048]
  const int rq = qb * 128 + w * 16;

  f32x4 accO[8] = {};
  f32x4 accS[8];
  f32x4 corrF[8] = {};
  float mrun[4], lrun[4];
#pragma unroll
  for (int e = 0; e < 4; e++) { mrun[e] = -INFINITY; lrun[e] = 0.f; }

  auto stageK = [&](const u16* kbase, int t) {
#pragma unroll
    for (int i = 0; i < 4; i++) {
      int r = w * 16 + i * 4 + (l >> 4);
      int s = l & 15;
      gll16(kbase + (size_t)t * 128 * DH + r * DH + ((s ^ (r & 15)) * 8),
            KA + (w * 16 + i * 4) * 128);
    }
  };
  auto stageV = [&](const u16* vbase, int t) {
#pragma unroll
    for (int i = 0; i < 4; i++) {
      int r = w * 16 + i * 4 + (l >> 4);
      int s = l & 15;
      gll16(vbase + (size_t)r * S_LEN + t * 128 + ((s ^ (r & 15)) * 8),
            VB + (w * 16 + i * 4) * 128);
    }
  };

  // ---- fused diag-correction prologue (block-uniform branch)
  if (hasDiag) {
    stageK(ku, qb);
    stageV(vuT, qb);
    s16x8 aqu[4];
#pragma unroll
    for (int ks = 0; ks < 4; ks++)
      aqu[ks] = *reinterpret_cast<const s16x8*>(
          qu + (size_t)(rq + lr) * DH + ks * 32 + lg * 8);
    asm volatile("s_waitcnt vmcnt(4)" ::: "memory");  // K_u in
    __syncthreads();
    f32x4 s2[8] = {};
#pragma unroll
    for (int ks = 0; ks < 4; ks++)
#pragma unroll
      for (int nf = 0; nf < 8; nf++) {
        int o = ((nf * 16 + lr) * 256 + ks * 64 + lg * 16) ^ (lr << 4);
        s16x8 b = *reinterpret_cast<const s16x8*>((const char*)KA + o);
        s2[nf] = mfma16(aqu[ks], b, s2[nf]);
      }
    asm volatile("s_waitcnt vmcnt(0)" ::: "memory");  // V_u in
    __syncthreads();
#pragma unroll
    for (int qq = 0; qq < 4; qq++) {
#pragma unroll
      for (int jj = 0; jj < 2; jj++)
#pragma unroll
        for (int e = 0; e < 4; e++) {
          int rowq = w * 16 + lg * 4 + e;
          int col = (qq * 2 + jj) * 16 + lr;
          float x = s2[qq * 2 + jj][e];
          PB[w * 16 + lg * 4 + e][jj * 16 + lr] =
              f2b((col > rowq) ? 1.f / (1.f + __expf(-x)) : 0.f);
        }
      s16x8 p = *reinterpret_cast<const s16x8*>(&PB[w * 16 + lr][lg * 8]);
#pragma unroll
      for (int nf = 0; nf < 8; nf++) {
        int o = ((nf * 16 + lr) * 256 + qq * 64 + lg * 16) ^ (lr << 4);
        s16x8 bv = *reinterpret_cast<const s16x8*>((const char*)VB + o);
        corrF[nf] = mfma16(p, bv, corrF[nf]);
      }
    }
#pragma unroll
    for (int nf = 0; nf < 8; nf++)
#pragma unroll
      for (int e = 0; e < 4; e++) {
        float x = corrF[nf][e];
        corrF[nf][e] = x / (1.f + __expf(-x));  // silu, kept in f32
      }
    __syncthreads();  // all waves done with KA/VB before main restage
  }

  // Q fragments in registers (once per slot)
  s16x8 aq[4];
#pragma unroll
  for (int ks = 0; ks < 4; ks++)
    aq[ks] = *reinterpret_cast<const s16x8*>(
        qc + (size_t)(rq + lr) * DH + ks * 32 + lg * 8);

  auto qkTile = [&](bool dg) {
#pragma unroll
    for (int nf = 0; nf < 8; nf++) accS[nf] = f32x4{0.f, 0.f, 0.f, 0.f};
#pragma unroll
    for (int ks = 0; ks < 4; ks++)
#pragma unroll
      for (int nf = 0; nf < 8; nf++) {
        int o = ((nf * 16 + lr) * 256 + ks * 64 + lg * 16) ^ (lr << 4);
        s16x8 b = *reinterpret_cast<const s16x8*>((const char*)KA + o);
        accS[nf] = mfma16(aq[ks], b, accS[nf]);
      }
    if (dg) {
#pragma unroll
      for (int nf = 0; nf < 8; nf++)
#pragma unroll
        for (int e = 0; e < 4; e++) {
          int rowq = w * 16 + lg * 4 + e;
          int col = nf * 16 + lr;
          if (col > rowq) accS[nf][e] = -INFINITY;
          else accS[nf][e] -= corrF[nf][e];
        }
    }
    // online softmax
#pragma unroll
    for (int e = 0; e < 4; e++) {
      float mx = accS[0][e];
#pragma unroll
      for (int nf = 1; nf < 8; nf++) mx = fmaxf(mx, accS[nf][e]);
#pragma unroll
      for (int off = 1; off < 16; off <<= 1) mx = fmaxf(mx, __shfl_xor(mx, off, 64));
      float mnew = fmaxf(mrun[e], mx);
      float f = __expf(mrun[e] - mnew);
      float rs = 0.f;
#pragma unroll
      for (int nf = 0; nf < 8; nf++) {
        float p = __expf(accS[nf][e] - mnew);
        accS[nf][e] = p;
        rs += p;
      }
#pragma unroll
      for (int off = 1; off < 16; off <<= 1) rs += __shfl_xor(rs, off, 64);
      lrun[e] = lrun[e] * f + rs;
      mrun[e] = mnew;
#pragma unroll
      for (int nf = 0; nf < 8; nf++) accO[nf][e] *= f;
    }
  };
  auto pvTile = [&]() {
#pragma unroll
    for (int qq = 0; qq < 4; qq++) {   // 32-key quarters; PB wave-private
#pragma unroll
      for (int jj = 0; jj < 2; jj++)
#pragma unroll
        for (int e = 0; e < 4; e++)
          PB[w * 16 + lg * 4 + e][jj * 16 + lr] = f2b(accS[qq * 2 + jj][e]);
      s16x8 p = *reinterpret_cast<const s16x8*>(&PB[w * 16 + lr][lg * 8]);
#pragma unroll
      for (int nf = 0; nf < 8; nf++) {
        int o = ((nf * 16 + lr) * 256 + qq * 64 + lg * 16) ^ (lr << 4);
        s16x8 bv = *reinterpret_cast<const s16x8*>((const char*)VB + o);
        accO[nf] = mfma16(p, bv, accO[nf]);
      }
    }
  };

  stageK(kc, t0);
  stageV(vcT, t0);
  asm volatile("s_waitcnt vmcnt(4)" ::: "memory");  // K(t0) in; V in flight
  __syncthreads();
  for (int i = 0; i < ntile; i++) {
    qkTile(t0 + i == qb);                            // V(i) lands under this
    asm volatile("s_waitcnt vmcnt(0)" ::: "memory"); // V(i) in
    __syncthreads();                                 // all waves done with KA
    if (i + 1 < ntile) stageK(kc, t0 + i + 1);       // overwrite KA
    pvTile();                                        // K(i+1) lands under this
    asm volatile("s_waitcnt vmcnt(0)" ::: "memory"); // K(i+1) in
    __syncthreads();                                 // all waves done with VB
    if (i + 1 < ntile) stageV(vcT, t0 + i + 1);      // overwrite VB
  }

  if (slot < 2) {
    // single-chunk slot (qb 0,1): normalize and write obuf directly
#pragma unroll
    for (int nf = 0; nf < 8; nf++)
#pragma unroll
      for (int e = 0; e < 4; e++) {
        int row = w * 16 + lg * 4 + e;
        KA[row * 128 + nf * 16 + lr] = f2b(accO[nf][e] / lrun[e]);
      }
    __syncthreads();
#pragma unroll
    for (int i = 0; i < 4; i++) {
      int idx = tid + i * 512;          // 2048 x s16x8 covers 128x128
      int row = idx >> 4, c8 = (idx & 15) * 8;
      *reinterpret_cast<s16x8*>(obuf + (size_t)(qb * 128 + row) * DMODEL +
                                h * DH + c8) =
          reinterpret_cast<const s16x8*>(KA)[idx];
    }
  } else {
    // coalesced partial writeout: accO -> KA (LDS) -> global
#pragma unroll
    for (int nf = 0; nf < 8; nf++)
#pragma unroll
      for (int e = 0; e < 4; e++) {
        int row = w * 16 + lg * 4 + e;
        KA[row * 128 + nf * 16 + lr] = f2b(accO[nf][e]);
      }
    __syncthreads();
    const int gs = h * 58 + slot - 2;   // 464 storage slots
    u16* dst = op + (size_t)gs * 16384;
#pragma unroll
    for (int i = 0; i < 4; i++)
      reinterpret_cast<s16x8*>(dst)[tid + i * 512] =
          reinterpret_cast<const s16x8*>(KA)[tid + i * 512];
    if (lr == 0) {
      float* mlp = ml + (size_t)gs * 256;
#pragma unroll
      for (int e = 0; e < 4; e++) {
        int row = w * 16 + lg * 4 + e;
        mlp[row] = mrun[e];
        mlp[128 + row] = lrun[e];
      }
    }
  }
}

// ---------------------------------------------------------------- phase 2 merge
// grid 112: h = bid&7, qb = 2 + (bid>>3). Chunk c of qb is storage slot
// gs = h*58 + S0T2[qb] + c.
__global__ void __launch_bounds__(256)
k_attn2(const u16* __restrict__ op, const float* __restrict__ ml,
        u16* __restrict__ obuf) {
  const int h = blockIdx.x & 7, qb = 2 + (blockIdx.x >> 3);
  const int nc = NCT2[qb];
  const int base = h * 58 + S0T2[qb];
  const int row = threadIdx.x >> 1, c0 = (threadIdx.x & 1) * 64;
  float mg = -INFINITY;
  for (int c = 0; c < nc; c++) mg = fmaxf(mg, ml[(size_t)(base + c) * 256 + row]);
  float acc[64];
#pragma unroll
  for (int k = 0; k < 64; k++) acc[k] = 0.f;
  float lsum = 0.f;
  for (int c = 0; c < nc; c++) {
    int gs = base + c;
    const float* mlp = ml + (size_t)gs * 256;
    float f = __expf(mlp[row] - mg);
    lsum += f * mlp[128 + row];
    const u16* p = op + (size_t)gs * 16384 + row * 128 + c0;
#pragma unroll
    for (int k = 0; k < 8; k++) {
      s16x8 v = *reinterpret_cast<const s16x8*>(p + k * 8);
#pragma unroll
      for (int j = 0; j < 8; j++) acc[k * 8 + j] += f * b2f((u16)v[j]);
    }
  }
  float inv = 1.f / lsum;
  u16* dst = obuf + (size_t)(qb * 128 + row) * DMODEL + h * DH + c0;
#pragma unroll
  for (int k = 0; k < 8; k++) {
    s16x8 o;
#pragma unroll
    for (int j = 0; j < 8; j++) o[j] = (short)f2b(acc[k * 8 + j] * inv);
    *reinterpret_cast<s16x8*>(dst + k * 8) = o;
  }
}

// ---------------------------------------------------------------- launcher
extern "C" void kernel_launch(void* const* d_in, const int* in_sizes, int n_in,
                              void* d_out, int out_size, void* d_ws, size_t ws_size,
                              hipStream_t stream) {
  (void)in_sizes; (void)n_in; (void)out_size; (void)ws_size;
  const float* x = (const float*)d_in[0];
  const float* wqkv = (const float*)d_in[1];
  const float* wout = (const float*)d_in[2];
  char* ws = (char*)d_ws;
  u16* xb    = (u16*)(ws + 0);          // 4 MB; dead after gemm0
  u16* wqT   = (u16*)(ws + 4194304);    // 12.58 MB; dead after gemm0
  u16* opb   = (u16*)(ws + 0);          // partials: 464 slots * 32 KB = 15.2 MB
  float* mlb = (float*)(ws + 15990784); // 464 * 256 * 4 = 0.48 MB
  u16* woT   = (u16*)(ws + 16777216);   // 2 MB (live until gemm1)
  u16* qkvb  = (u16*)(ws + 18874368);   // 24 MB: [qu|ku|vuT|qc|kc|vcT]
  u16* obuf  = (u16*)(ws + 44040192);   // 4 MB
  float* out = (float*)d_out;

  k_prep<<<3840, 256, 0, stream>>>(x, wqkv, wout, xb, wqT, woT);
  k_gemm2<0><<<768, 256, 0, stream>>>(xb, wqT, qkvb, nullptr);
  k_attn1<<<480, 512, 0, stream>>>(qkvb, opb, mlb, obuf);
  k_attn2<<<112, 256, 0, stream>>>(opb, mlb, obuf);
  k_gemm2<1><<<dim3(8, 32), 256, 0, stream>>>(obuf, woT, nullptr, out);
}